// Round 5
// baseline (1624.568 us; speedup 1.0000x reference)
//
#include <hip/hip_runtime.h>
#include <hip/hip_fp16.h>
#include <cmath>

#define NROWS  65536
#define DIM    512
#define KCODES 2048
#define NDTOT  33554432LL   // NROWS*DIM
#define MARGIN 0.0625f      // = 14 sigma of f16-product distance error (4.5e-3)

typedef __attribute__((ext_vector_type(8))) _Float16 f16x8;  // 8 f16 = 1 MFMA operand
typedef __attribute__((ext_vector_type(4))) float f32x4;

__device__ inline void gll16(const void* g, void* l) {
    __builtin_amdgcn_global_load_lds(
        (const __attribute__((address_space(1))) void*)g,
        (__attribute__((address_space(3))) void*)l, 16, 0, 0);
}

// ---------------- kernel 1: fp32 -> f16 plane in fragment-lane order, fused row norm ----
// tile (per 128-row block rb, per ks64 of 64 dims): 16384 B =
//   [ksub 2][frow 8][lane 64][16B]; lane = (k32sub)*16 + row%16, frow=(row%128)/16.
// Matches mfma_f32_16x16x32_f16 A/B frags (lane l: row l&15, k=(l>>4)*8+r).
__global__ __launch_bounds__(256) void k_prep(const float* __restrict__ src,
                                              char* __restrict__ dst,
                                              float* __restrict__ norms) {
    long gid = (long)blockIdx.x * 256 + threadIdx.x;
    int row = (int)(gid >> 6);
    int k8  = (int)(gid & 63);           // chunk of 8 dims
    const float4* s = (const float4*)(src + (size_t)row * DIM + k8 * 8);
    float4 v0 = s[0], v1 = s[1];
    float vv[8] = {v0.x, v0.y, v0.z, v0.w, v1.x, v1.y, v1.z, v1.w};
    unsigned int hw[4];
    float nrm = 0.f;
    #pragma unroll
    for (int j = 0; j < 4; ++j) {
        unsigned int h0 = __half_as_ushort(__float2half_rn(vv[2*j]));
        unsigned int h1 = __half_as_ushort(__float2half_rn(vv[2*j+1]));
        hw[j] = h0 | (h1 << 16);
        nrm = fmaf(vv[2*j], vv[2*j], nrm);
        nrm = fmaf(vv[2*j+1], vv[2*j+1], nrm);
    }
    int rb = row >> 7, frow = (row >> 4) & 7;
    int k32 = k8 >> 2, sub = k8 & 3;
    int ksub = k32 & 1, ks64 = k32 >> 1;
    int l = sub * 16 + (row & 15);
    size_t off = (size_t)(rb * 8 + ks64) * 16384 + (size_t)ksub * 8192
               + (size_t)frow * 1024 + (size_t)l * 16;
    *(uint4*)(dst + off) = make_uint4(hw[0], hw[1], hw[2], hw[3]);
    #pragma unroll
    for (int o = 32; o; o >>= 1) nrm += __shfl_xor(nrm, o, 64);
    if ((threadIdx.x & 63) == 0) norms[row] = nrm;
}

// ---------------- kernel 2: f16 MFMA GEMM + fused top-3 argmin ----------------
// 512 blocks (2/CU at 64KB LDS), 4 waves of 64x64 out, cb-outer (16 x 128 codes),
// ks64-inner (8 x K=64), proven r3-style 2-phase dbuf (__syncthreads, no asm).
__global__ __launch_bounds__(256, 2) void k_gemm(const char* __restrict__ xp,
                                                 const char* __restrict__ wp,
                                                 const float* __restrict__ wnorm,
                                                 int* __restrict__ idxo,
                                                 int* __restrict__ cand2o,
                                                 int* __restrict__ cand3o,
                                                 float* __restrict__ bestd) {
    __shared__ char smem[65536];   // As[2] @0,16384 ; Bs[2] @32768,49152
    const int tid = threadIdx.x;
    const int lane = tid & 63;
    const int wid = tid >> 6;
    const int wr = wid >> 1, wc = wid & 1;
    const int rb = blockIdx.x;
    const char* xsrc = xp + (size_t)rb * (8 * 16384);

    f32x4 acc[4][4];
    #pragma unroll
    for (int i = 0; i < 4; ++i)
        #pragma unroll
        for (int j = 0; j < 4; ++j) acc[i][j] = (f32x4){0.f, 0.f, 0.f, 0.f};

    float d1[16], d2[16], d3[16]; int i1[16], i2[16], i3[16];
    #pragma unroll
    for (int s = 0; s < 16; ++s) { d1[s] = d2[s] = d3[s] = 3.4e38f; i1[s] = i2[s] = i3[s] = 0; }

    auto STAGE = [&](int t) {
        int cb = t >> 3, ks = t & 7, p = t & 1;
        const char* bsrc = wp + (size_t)(cb * 8 + ks) * 16384;
        const char* asrc = xsrc + (size_t)ks * 16384;
        char* bdst = smem + 32768 + p * 16384;
        char* adst = smem + p * 16384;
        #pragma unroll
        for (int i = 0; i < 4; ++i) {
            int c = wid * 4 + i;   // 16 chunks of 1024B per matrix, 4 per wave
            gll16(bsrc + c * 1024 + lane * 16, bdst + c * 1024);
            gll16(asrc + c * 1024 + lane * 16, adst + c * 1024);
        }
    };

    auto COMPUTE = [&](int t) {
        int p = t & 1;
        const char* A = smem + p * 16384;
        const char* B = smem + 32768 + p * 16384;
        #pragma unroll
        for (int ksub = 0; ksub < 2; ++ksub) {
            f16x8 ah[4];
            #pragma unroll
            for (int fr = 0; fr < 4; ++fr)
                ah[fr] = *(const f16x8*)(A + ksub * 8192 + (wr * 4 + fr) * 1024 + lane * 16);
            #pragma unroll
            for (int fc = 0; fc < 4; ++fc) {
                f16x8 bh = *(const f16x8*)(B + ksub * 8192 + (wc * 4 + fc) * 1024 + lane * 16);
                #pragma unroll
                for (int fr = 0; fr < 4; ++fr)
                    acc[fr][fc] = __builtin_amdgcn_mfma_f32_16x16x32_f16(ah[fr], bh, acc[fr][fc], 0, 0, 0);
            }
        }
    };

    auto EPILOGUE = [&](int cb) {
        #pragma unroll
        for (int fc = 0; fc < 4; ++fc) {
            int col = cb * 128 + wc * 64 + fc * 16 + (lane & 15);
            float wn = wnorm[col];
            #pragma unroll
            for (int fr = 0; fr < 4; ++fr) {
                #pragma unroll
                for (int reg = 0; reg < 4; ++reg) {
                    float dist = fmaf(-2.f, acc[fr][fc][reg], wn);
                    int s = fr * 4 + reg;
                    // cols arrive in ascending order per slot -> strict < keeps lowest idx
                    if (dist < d1[s]) { d3[s]=d2[s]; i3[s]=i2[s]; d2[s]=d1[s]; i2[s]=i1[s]; d1[s]=dist; i1[s]=col; }
                    else if (dist < d2[s]) { d3[s]=d2[s]; i3[s]=i2[s]; d2[s]=dist; i2[s]=col; }
                    else if (dist < d3[s]) { d3[s]=dist; i3[s]=col; }
                }
                acc[fr][fc] = (f32x4){0.f, 0.f, 0.f, 0.f};
            }
        }
    };

    STAGE(0);
    __syncthreads();
    #pragma unroll 2
    for (int t = 0; t < 128; ++t) {
        if (t < 127) STAGE(t + 1);
        COMPUTE(t);
        if ((t & 7) == 7) EPILOGUE(t >> 3);
        __syncthreads();
    }

    // lex insert helper: (d,c) into sorted triple
    auto INS = [](float& D1,int& I1,float& D2,int& I2,float& D3,int& I3, float d,int c) {
        bool l1 = (d < D1) || (d == D1 && c < I1);
        bool l2 = (d < D2) || (d == D2 && c < I2);
        bool l3 = (d < D3) || (d == D3 && c < I3);
        if (l1)      { D3=D2;I3=I2; D2=D1;I2=I1; D1=d;I1=c; }
        else if (l2) { D3=D2;I3=I2; D2=d;I2=c; }
        else if (l3) { D3=d;I3=c; }
    };

    // butterfly top-3 merge across the 16 column-lanes of each slot
    #pragma unroll
    for (int s = 0; s < 16; ++s) {
        #pragma unroll
        for (int off = 1; off < 16; off <<= 1) {
            float od1 = __shfl_xor(d1[s], off, 16); int oi1 = __shfl_xor(i1[s], off, 16);
            float od2 = __shfl_xor(d2[s], off, 16); int oi2 = __shfl_xor(i2[s], off, 16);
            float od3 = __shfl_xor(d3[s], off, 16); int oi3 = __shfl_xor(i3[s], off, 16);
            INS(d1[s],i1[s],d2[s],i2[s],d3[s],i3[s], od1,oi1);
            INS(d1[s],i1[s],d2[s],i2[s],d3[s],i3[s], od2,oi2);
            INS(d1[s],i1[s],d2[s],i2[s],d3[s],i3[s], od3,oi3);
        }
    }
    // lane (lane&15)==s owns slot s; static-unrolled select (rule #20)
    float md1=0.f, md2=0.f, md3=0.f; int mi1=0, mi2=0, mi3=0;
    #pragma unroll
    for (int s = 0; s < 16; ++s) {
        bool mine = (lane & 15) == s;
        md1 = mine ? d1[s] : md1; mi1 = mine ? i1[s] : mi1;
        md2 = mine ? d2[s] : md2; mi2 = mine ? i2[s] : mi2;
        md3 = mine ? d3[s] : md3; mi3 = mine ? i3[s] : mi3;
    }
    int sl = lane & 15;
    int rowl = wr * 64 + (sl >> 2) * 16 + (lane >> 4) * 4 + (sl & 3);
    float* slot = (float*)smem + (rowl * 2 + wc) * 8;
    slot[0]=md1; slot[1]=__int_as_float(mi1);
    slot[2]=md2; slot[3]=__int_as_float(mi2);
    slot[4]=md3; slot[5]=__int_as_float(mi3);
    __syncthreads();
    if (tid < 128) {
        const float* e0 = (const float*)smem + (tid * 2 + 0) * 8;
        const float* e1 = (const float*)smem + (tid * 2 + 1) * 8;
        float D1=e0[0], D2=e0[2], D3=e0[4];
        int   I1=__float_as_int(e0[1]), I2=__float_as_int(e0[3]), I3=__float_as_int(e0[5]);
        INS(D1,I1,D2,I2,D3,I3, e1[0], __float_as_int(e1[1]));
        INS(D1,I1,D2,I2,D3,I3, e1[2], __float_as_int(e1[3]));
        INS(D1,I1,D2,I2,D3,I3, e1[4], __float_as_int(e1[5]));
        int row = rb * 128 + tid;
        idxo[row]   = I1;
        bestd[row]  = D1;
        cand2o[row] = (D2 - D1 < MARGIN) ? I2 : -1;
        cand3o[row] = (D3 - D1 < MARGIN) ? I3 : -1;
    }
}

// ---------------- kernel 3: fp64 refinement among up to 3 candidates ----------------
__global__ __launch_bounds__(256) void k_refine(const float* __restrict__ x,
                                                const float* __restrict__ w,
                                                int* __restrict__ idxo,
                                                const int* __restrict__ cand2o,
                                                const int* __restrict__ cand3o,
                                                float* __restrict__ bestd) {
    int wid = threadIdx.x >> 6, lane = threadIdx.x & 63;
    int n = blockIdx.x * 4 + wid;
    int c2 = cand2o[n];
    if (c2 < 0) return;
    int c1 = idxo[n];
    int c3 = cand3o[n];
    int c3e = (c3 < 0) ? c1 : c3;
    const float* xr = x + (size_t)n * DIM;
    const float* w1 = w + (size_t)c1 * DIM;
    const float* w2 = w + (size_t)c2 * DIM;
    const float* w3 = w + (size_t)c3e * DIM;
    double s1 = 0.0, s2 = 0.0, s3 = 0.0;
    #pragma unroll
    for (int j = 0; j < DIM / 64; ++j) {
        int d = lane + 64 * j;
        double xv = (double)xr[d];
        double a = (double)w1[d], b = (double)w2[d], c = (double)w3[d];
        s1 += a * a - 2.0 * xv * a;
        s2 += b * b - 2.0 * xv * b;
        s3 += c * c - 2.0 * xv * c;
    }
    #pragma unroll
    for (int off = 32; off; off >>= 1) {
        s1 += __shfl_xor(s1, off, 64);
        s2 += __shfl_xor(s2, off, 64);
        s3 += __shfl_xor(s3, off, 64);
    }
    if (lane == 0) {
        double bs = s1; int bi = c1;
        if (s2 < bs || (s2 == bs && c2 < bi)) { bs = s2; bi = c2; }
        if (c3 >= 0 && (s3 < bs || (s3 == bs && c3 < bi))) { bs = s3; bi = c3; }
        idxo[n]  = bi;
        bestd[n] = (float)bs;   // exact (||w||^2 - 2 x.w) for loss
    }
}

// ---------------- kernel 4: gather + loss-from-distance + histogram + index out ----------------
__global__ __launch_bounds__(256) void k_gather(const float* __restrict__ w,
                                                const int* __restrict__ idxo,
                                                const float* __restrict__ bestd,
                                                const float* __restrict__ xnorm,
                                                float* __restrict__ out,
                                                int* __restrict__ hist,
                                                float* __restrict__ lossp) {
    int wid = threadIdx.x >> 6, lane = threadIdx.x & 63;
    int n = blockIdx.x * 4 + wid;
    int c = idxo[n];
    const float* wq = w + (size_t)c * DIM;
    float* oq = out + 1 + (size_t)n * DIM;   // quantized_st == quantized numerically
    #pragma unroll
    for (int j = 0; j < DIM / 64; ++j) {
        int d = j * 64 + lane;
        oq[d] = wq[d];
    }
    if (lane == 0) {
        lossp[n] = bestd[n] + xnorm[n];      // ||x-w||^2
        atomicAdd(&hist[c], 1);
        out[2 + NDTOT + n] = (float)c;
    }
}

// ---------------- kernel 5a: loss partial sums (64 blocks) ----------------
__global__ __launch_bounds__(256) void k_loss1(const float* __restrict__ lossp,
                                               double* __restrict__ part) {
    __shared__ double sm[256];
    int t = threadIdx.x;
    float4 v = ((const float4*)lossp)[blockIdx.x * 256 + t];
    sm[t] = (double)v.x + (double)v.y + (double)v.z + (double)v.w;
    __syncthreads();
    for (int off = 128; off; off >>= 1) { if (t < off) sm[t] += sm[t + off]; __syncthreads(); }
    if (t == 0) part[blockIdx.x] = sm[0];
}

// ---------------- kernel 5b: deterministic finalize ----------------
__global__ __launch_bounds__(256) void k_final2(const double* __restrict__ part,
                                                const int* __restrict__ hist,
                                                float* __restrict__ out) {
    __shared__ double sm[256];
    int t = threadIdx.x;
    sm[t] = (t < 64) ? part[t] : 0.0;
    __syncthreads();
    for (int off = 128; off; off >>= 1) { if (t < off) sm[t] += sm[t + off]; __syncthreads(); }
    if (t == 0) out[0] = (float)(sm[0] * 0.25 / (double)NDTOT);
    __syncthreads();
    double e = 0.0;
    for (int k = t; k < KCODES; k += 256) {
        double p = (double)hist[k] / (double)NROWS;
        e -= p * log(p + 1e-10);
    }
    sm[t] = e; __syncthreads();
    for (int off = 128; off; off >>= 1) { if (t < off) sm[t] += sm[t + off]; __syncthreads(); }
    if (t == 0) out[1 + NDTOT] = (float)exp(sm[0]);
}

extern "C" void kernel_launch(void* const* d_in, const int* in_sizes, int n_in,
                              void* d_out, int out_size, void* d_ws, size_t ws_size,
                              hipStream_t stream) {
    const float* x = (const float*)d_in[0];   // [64,1024,512] fp32
    const float* w = (const float*)d_in[1];   // [2048,512] fp32
    float* out = (float*)d_out;
    char* ws = (char*)d_ws;

    // xp (64 MB f16 fragment-ordered) lives in the d_out quantized region:
    // k_gemm consumes it before k_gather overwrites that region.
    char* xp = (char*)d_out + 16;

    char*   wp    = ws;                            // 2 MB
    float*  wnorm = (float*)(ws + 2097152);        // 8 KB
    int*    idxo  = (int*)(ws + 2105344);          // 256 KB
    int*    cand2 = (int*)(ws + 2367488);          // 256 KB
    int*    cand3 = (int*)(ws + 2629632);          // 256 KB
    int*    hist  = (int*)(ws + 2891776);          // 8 KB
    float*  lossp = (float*)(ws + 2899968);        // 256 KB
    float*  xnorm = (float*)(ws + 3162112);        // 256 KB
    float*  bestd = (float*)(ws + 3424256);        // 256 KB
    double* part  = (double*)(ws + 3686400);       // 512 B

    hipMemsetAsync(hist, 0, KCODES * sizeof(int), stream);
    k_prep   <<<(KCODES * 64) / 256, 256, 0, stream>>>(w, wp, wnorm);
    k_prep   <<<(NROWS * 64) / 256, 256, 0, stream>>>(x, xp, xnorm);
    k_gemm   <<<NROWS / 128, 256, 0, stream>>>(xp, wp, wnorm, idxo, cand2, cand3, bestd);
    k_refine <<<NROWS / 4, 256, 0, stream>>>(x, w, idxo, cand2, cand3, bestd);
    k_gather <<<NROWS / 4, 256, 0, stream>>>(w, idxo, bestd, xnorm, out, hist, lossp);
    k_loss1  <<<64, 256, 0, stream>>>(lossp, part);
    k_final2 <<<1, 256, 0, stream>>>(part, hist, out);
}

// Round 6
// 408.198 us; speedup vs baseline: 3.9799x; 3.9799x over previous
//
#include <hip/hip_runtime.h>
#include <hip/hip_fp16.h>
#include <cmath>

#define NROWS  65536
#define DIM    512
#define KCODES 2048
#define NDTOT  33554432LL   // NROWS*DIM
#define MARGIN 0.0625f      // = 14 sigma of f16-product distance error (4.5e-3)

typedef __attribute__((ext_vector_type(8))) _Float16 f16x8;  // 8 f16 = 1 MFMA operand
typedef __attribute__((ext_vector_type(4))) float f32x4;

// sorted top-3 insert as a MACRO: operands stay direct l-values (no address
// taken -> arrays remain SROA-able registers; the r5 lambda版 spilled to scratch)
#define INS3(D1,I1,D2,I2,D3,I3,dd,cc) do {                                  \
    float _d = (dd); int _c = (cc);                                         \
    bool _l1 = (_d < (D1)) || (_d == (D1) && _c < (I1));                    \
    bool _l2 = (_d < (D2)) || (_d == (D2) && _c < (I2));                    \
    bool _l3 = (_d < (D3)) || (_d == (D3) && _c < (I3));                    \
    if (_l1)      { (D3)=(D2);(I3)=(I2); (D2)=(D1);(I2)=(I1); (D1)=_d;(I1)=_c; } \
    else if (_l2) { (D3)=(D2);(I3)=(I2); (D2)=_d;(I2)=_c; }                 \
    else if (_l3) { (D3)=_d;(I3)=_c; }                                      \
} while (0)

__device__ inline void gll16(const void* g, void* l) {
    __builtin_amdgcn_global_load_lds(
        (const __attribute__((address_space(1))) void*)g,
        (__attribute__((address_space(3))) void*)l, 16, 0, 0);
}

// ---------------- kernel 1: fp32 -> f16 plane in fragment-lane order, fused row norm ----
// tile (per 128-row block rb, per ks64 of 64 dims): 16384 B =
//   [ksub 2][frow 8][lane 64][16B]; lane = (k32sub)*16 + row%16, frow=(row%128)/16.
// Matches mfma_f32_16x16x32_f16 A/B frags (lane l: row l&15, k=(l>>4)*8+r).
__global__ __launch_bounds__(256) void k_prep(const float* __restrict__ src,
                                              char* __restrict__ dst,
                                              float* __restrict__ norms) {
    long gid = (long)blockIdx.x * 256 + threadIdx.x;
    int row = (int)(gid >> 6);
    int k8  = (int)(gid & 63);           // chunk of 8 dims
    const float4* s = (const float4*)(src + (size_t)row * DIM + k8 * 8);
    float4 v0 = s[0], v1 = s[1];
    float vv[8] = {v0.x, v0.y, v0.z, v0.w, v1.x, v1.y, v1.z, v1.w};
    unsigned int hw[4];
    float nrm = 0.f;
    #pragma unroll
    for (int j = 0; j < 4; ++j) {
        unsigned int h0 = __half_as_ushort(__float2half_rn(vv[2*j]));
        unsigned int h1 = __half_as_ushort(__float2half_rn(vv[2*j+1]));
        hw[j] = h0 | (h1 << 16);
        nrm = fmaf(vv[2*j], vv[2*j], nrm);
        nrm = fmaf(vv[2*j+1], vv[2*j+1], nrm);
    }
    int rb = row >> 7, frow = (row >> 4) & 7;
    int k32 = k8 >> 2, sub = k8 & 3;
    int ksub = k32 & 1, ks64 = k32 >> 1;
    int l = sub * 16 + (row & 15);
    size_t off = (size_t)(rb * 8 + ks64) * 16384 + (size_t)ksub * 8192
               + (size_t)frow * 1024 + (size_t)l * 16;
    *(uint4*)(dst + off) = make_uint4(hw[0], hw[1], hw[2], hw[3]);
    #pragma unroll
    for (int o = 32; o; o >>= 1) nrm += __shfl_xor(nrm, o, 64);
    if ((threadIdx.x & 63) == 0) norms[row] = nrm;
}

// ---------------- kernel 2: f16 MFMA GEMM + fused top-3 argmin ----------------
// 512 blocks (2/CU at 64KB LDS), 4 waves of 64x64 out, cb-outer (16 x 128 codes),
// ks64-inner (8 x K=64), proven r3-style 2-phase dbuf (__syncthreads, no asm).
__global__ __launch_bounds__(256, 2) void k_gemm(const char* __restrict__ xp,
                                                 const char* __restrict__ wp,
                                                 const float* __restrict__ wnorm,
                                                 int* __restrict__ idxo,
                                                 int* __restrict__ cand2o,
                                                 int* __restrict__ cand3o,
                                                 float* __restrict__ bestd) {
    __shared__ char smem[65536];   // As[2] @0,16384 ; Bs[2] @32768,49152
    const int tid = threadIdx.x;
    const int lane = tid & 63;
    const int wid = tid >> 6;
    const int wr = wid >> 1, wc = wid & 1;
    const int rb = blockIdx.x;
    const char* xsrc = xp + (size_t)rb * (8 * 16384);

    f32x4 acc[4][4];
    #pragma unroll
    for (int i = 0; i < 4; ++i)
        #pragma unroll
        for (int j = 0; j < 4; ++j) acc[i][j] = (f32x4){0.f, 0.f, 0.f, 0.f};

    float d1[16], d2[16], d3[16]; int i1[16], i2[16], i3[16];
    #pragma unroll
    for (int s = 0; s < 16; ++s) { d1[s] = d2[s] = d3[s] = 3.4e38f; i1[s] = i2[s] = i3[s] = 0; }

    auto STAGE = [&](int t) {
        int cb = t >> 3, ks = t & 7, p = t & 1;
        const char* bsrc = wp + (size_t)(cb * 8 + ks) * 16384;
        const char* asrc = xsrc + (size_t)ks * 16384;
        char* bdst = smem + 32768 + p * 16384;
        char* adst = smem + p * 16384;
        #pragma unroll
        for (int i = 0; i < 4; ++i) {
            int c = wid * 4 + i;   // 16 chunks of 1024B per matrix, 4 per wave
            gll16(bsrc + c * 1024 + lane * 16, bdst + c * 1024);
            gll16(asrc + c * 1024 + lane * 16, adst + c * 1024);
        }
    };

    auto COMPUTE = [&](int t) {
        int p = t & 1;
        const char* A = smem + p * 16384;
        const char* B = smem + 32768 + p * 16384;
        #pragma unroll
        for (int ksub = 0; ksub < 2; ++ksub) {
            f16x8 ah[4];
            #pragma unroll
            for (int fr = 0; fr < 4; ++fr)
                ah[fr] = *(const f16x8*)(A + ksub * 8192 + (wr * 4 + fr) * 1024 + lane * 16);
            #pragma unroll
            for (int fc = 0; fc < 4; ++fc) {
                f16x8 bh = *(const f16x8*)(B + ksub * 8192 + (wc * 4 + fc) * 1024 + lane * 16);
                #pragma unroll
                for (int fr = 0; fr < 4; ++fr)
                    acc[fr][fc] = __builtin_amdgcn_mfma_f32_16x16x32_f16(ah[fr], bh, acc[fr][fc], 0, 0, 0);
            }
        }
    };

    auto EPILOGUE = [&](int cb) {
        #pragma unroll
        for (int fc = 0; fc < 4; ++fc) {
            int col = cb * 128 + wc * 64 + fc * 16 + (lane & 15);
            float wn = wnorm[col];
            #pragma unroll
            for (int fr = 0; fr < 4; ++fr) {
                #pragma unroll
                for (int reg = 0; reg < 4; ++reg) {
                    float dist = fmaf(-2.f, acc[fr][fc][reg], wn);
                    int s = fr * 4 + reg;
                    // cols arrive in ascending order per slot -> strict < keeps lowest idx
                    if (dist < d1[s]) { d3[s]=d2[s]; i3[s]=i2[s]; d2[s]=d1[s]; i2[s]=i1[s]; d1[s]=dist; i1[s]=col; }
                    else if (dist < d2[s]) { d3[s]=d2[s]; i3[s]=i2[s]; d2[s]=dist; i2[s]=col; }
                    else if (dist < d3[s]) { d3[s]=dist; i3[s]=col; }
                }
                acc[fr][fc] = (f32x4){0.f, 0.f, 0.f, 0.f};
            }
        }
    };

    STAGE(0);
    __syncthreads();
    #pragma unroll 2
    for (int t = 0; t < 128; ++t) {
        if (t < 127) STAGE(t + 1);
        COMPUTE(t);
        if ((t & 7) == 7) EPILOGUE(t >> 3);
        __syncthreads();
    }

    // butterfly top-3 merge across the 16 column-lanes of each slot
    #pragma unroll
    for (int s = 0; s < 16; ++s) {
        #pragma unroll
        for (int off = 1; off < 16; off <<= 1) {
            float od1 = __shfl_xor(d1[s], off, 16); int oi1 = __shfl_xor(i1[s], off, 16);
            float od2 = __shfl_xor(d2[s], off, 16); int oi2 = __shfl_xor(i2[s], off, 16);
            float od3 = __shfl_xor(d3[s], off, 16); int oi3 = __shfl_xor(i3[s], off, 16);
            INS3(d1[s],i1[s],d2[s],i2[s],d3[s],i3[s], od1,oi1);
            INS3(d1[s],i1[s],d2[s],i2[s],d3[s],i3[s], od2,oi2);
            INS3(d1[s],i1[s],d2[s],i2[s],d3[s],i3[s], od3,oi3);
        }
    }
    // lane (lane&15)==s owns slot s; static-unrolled select (rule #20)
    float md1=0.f, md2=0.f, md3=0.f; int mi1=0, mi2=0, mi3=0;
    #pragma unroll
    for (int s = 0; s < 16; ++s) {
        bool mine = (lane & 15) == s;
        md1 = mine ? d1[s] : md1; mi1 = mine ? i1[s] : mi1;
        md2 = mine ? d2[s] : md2; mi2 = mine ? i2[s] : mi2;
        md3 = mine ? d3[s] : md3; mi3 = mine ? i3[s] : mi3;
    }
    int sl = lane & 15;
    int rowl = wr * 64 + (sl >> 2) * 16 + (lane >> 4) * 4 + (sl & 3);
    float* slot = (float*)smem + (rowl * 2 + wc) * 8;
    slot[0]=md1; slot[1]=__int_as_float(mi1);
    slot[2]=md2; slot[3]=__int_as_float(mi2);
    slot[4]=md3; slot[5]=__int_as_float(mi3);
    __syncthreads();
    if (tid < 128) {
        const float* e0 = (const float*)smem + (tid * 2 + 0) * 8;
        const float* e1 = (const float*)smem + (tid * 2 + 1) * 8;
        float D1=e0[0], D2=e0[2], D3=e0[4];
        int   I1=__float_as_int(e0[1]), I2=__float_as_int(e0[3]), I3=__float_as_int(e0[5]);
        INS3(D1,I1,D2,I2,D3,I3, e1[0], __float_as_int(e1[1]));
        INS3(D1,I1,D2,I2,D3,I3, e1[2], __float_as_int(e1[3]));
        INS3(D1,I1,D2,I2,D3,I3, e1[4], __float_as_int(e1[5]));
        int row = rb * 128 + tid;
        idxo[row]   = I1;
        bestd[row]  = D1;
        cand2o[row] = (D2 - D1 < MARGIN) ? I2 : -1;
        cand3o[row] = (D3 - D1 < MARGIN) ? I3 : -1;
    }
}

// ---------------- kernel 3: fp64 refinement among up to 3 candidates ----------------
__global__ __launch_bounds__(256) void k_refine(const float* __restrict__ x,
                                                const float* __restrict__ w,
                                                int* __restrict__ idxo,
                                                const int* __restrict__ cand2o,
                                                const int* __restrict__ cand3o,
                                                float* __restrict__ bestd) {
    int wid = threadIdx.x >> 6, lane = threadIdx.x & 63;
    int n = blockIdx.x * 4 + wid;
    int c2 = cand2o[n];
    if (c2 < 0) return;
    int c1 = idxo[n];
    int c3 = cand3o[n];
    int c3e = (c3 < 0) ? c1 : c3;
    const float* xr = x + (size_t)n * DIM;
    const float* w1 = w + (size_t)c1 * DIM;
    const float* w2 = w + (size_t)c2 * DIM;
    const float* w3 = w + (size_t)c3e * DIM;
    double s1 = 0.0, s2 = 0.0, s3 = 0.0;
    #pragma unroll
    for (int j = 0; j < DIM / 64; ++j) {
        int d = lane + 64 * j;
        double xv = (double)xr[d];
        double a = (double)w1[d], b = (double)w2[d], c = (double)w3[d];
        s1 += a * a - 2.0 * xv * a;
        s2 += b * b - 2.0 * xv * b;
        s3 += c * c - 2.0 * xv * c;
    }
    #pragma unroll
    for (int off = 32; off; off >>= 1) {
        s1 += __shfl_xor(s1, off, 64);
        s2 += __shfl_xor(s2, off, 64);
        s3 += __shfl_xor(s3, off, 64);
    }
    if (lane == 0) {
        double bs = s1; int bi = c1;
        if (s2 < bs || (s2 == bs && c2 < bi)) { bs = s2; bi = c2; }
        if (c3 >= 0 && (s3 < bs || (s3 == bs && c3 < bi))) { bs = s3; bi = c3; }
        idxo[n]  = bi;
        bestd[n] = (float)bs;   // exact (||w||^2 - 2 x.w) for loss
    }
}

// ---------------- kernel 4: gather + loss-from-distance + histogram + index out ----------------
__global__ __launch_bounds__(256) void k_gather(const float* __restrict__ w,
                                                const int* __restrict__ idxo,
                                                const float* __restrict__ bestd,
                                                const float* __restrict__ xnorm,
                                                float* __restrict__ out,
                                                int* __restrict__ hist,
                                                float* __restrict__ lossp) {
    int wid = threadIdx.x >> 6, lane = threadIdx.x & 63;
    int n = blockIdx.x * 4 + wid;
    int c = idxo[n];
    const float* wq = w + (size_t)c * DIM;
    float* oq = out + 1 + (size_t)n * DIM;   // quantized_st == quantized numerically
    #pragma unroll
    for (int j = 0; j < DIM / 64; ++j) {
        int d = j * 64 + lane;
        oq[d] = wq[d];
    }
    if (lane == 0) {
        lossp[n] = bestd[n] + xnorm[n];      // ||x-w||^2
        atomicAdd(&hist[c], 1);
        out[2 + NDTOT + n] = (float)c;
    }
}

// ---------------- kernel 5a: loss partial sums (64 blocks) ----------------
__global__ __launch_bounds__(256) void k_loss1(const float* __restrict__ lossp,
                                               double* __restrict__ part) {
    __shared__ double sm[256];
    int t = threadIdx.x;
    float4 v = ((const float4*)lossp)[blockIdx.x * 256 + t];
    sm[t] = (double)v.x + (double)v.y + (double)v.z + (double)v.w;
    __syncthreads();
    for (int off = 128; off; off >>= 1) { if (t < off) sm[t] += sm[t + off]; __syncthreads(); }
    if (t == 0) part[blockIdx.x] = sm[0];
}

// ---------------- kernel 5b: deterministic finalize ----------------
__global__ __launch_bounds__(256) void k_final2(const double* __restrict__ part,
                                                const int* __restrict__ hist,
                                                float* __restrict__ out) {
    __shared__ double sm[256];
    int t = threadIdx.x;
    sm[t] = (t < 64) ? part[t] : 0.0;
    __syncthreads();
    for (int off = 128; off; off >>= 1) { if (t < off) sm[t] += sm[t + off]; __syncthreads(); }
    if (t == 0) out[0] = (float)(sm[0] * 0.25 / (double)NDTOT);
    __syncthreads();
    double e = 0.0;
    for (int k = t; k < KCODES; k += 256) {
        double p = (double)hist[k] / (double)NROWS;
        e -= p * log(p + 1e-10);
    }
    sm[t] = e; __syncthreads();
    for (int off = 128; off; off >>= 1) { if (t < off) sm[t] += sm[t + off]; __syncthreads(); }
    if (t == 0) out[1 + NDTOT] = (float)exp(sm[0]);
}

extern "C" void kernel_launch(void* const* d_in, const int* in_sizes, int n_in,
                              void* d_out, int out_size, void* d_ws, size_t ws_size,
                              hipStream_t stream) {
    const float* x = (const float*)d_in[0];   // [64,1024,512] fp32
    const float* w = (const float*)d_in[1];   // [2048,512] fp32
    float* out = (float*)d_out;
    char* ws = (char*)d_ws;

    // xp (64 MB f16 fragment-ordered) lives in the d_out quantized region:
    // k_gemm consumes it before k_gather overwrites that region.
    char* xp = (char*)d_out + 16;

    char*   wp    = ws;                            // 2 MB
    float*  wnorm = (float*)(ws + 2097152);        // 8 KB
    int*    idxo  = (int*)(ws + 2105344);          // 256 KB
    int*    cand2 = (int*)(ws + 2367488);          // 256 KB
    int*    cand3 = (int*)(ws + 2629632);          // 256 KB
    int*    hist  = (int*)(ws + 2891776);          // 8 KB
    float*  lossp = (float*)(ws + 2899968);        // 256 KB
    float*  xnorm = (float*)(ws + 3162112);        // 256 KB
    float*  bestd = (float*)(ws + 3424256);        // 256 KB
    double* part  = (double*)(ws + 3686400);       // 512 B

    hipMemsetAsync(hist, 0, KCODES * sizeof(int), stream);
    k_prep   <<<(KCODES * 64) / 256, 256, 0, stream>>>(w, wp, wnorm);
    k_prep   <<<(NROWS * 64) / 256, 256, 0, stream>>>(x, xp, xnorm);
    k_gemm   <<<NROWS / 128, 256, 0, stream>>>(xp, wp, wnorm, idxo, cand2, cand3, bestd);
    k_refine <<<NROWS / 4, 256, 0, stream>>>(x, w, idxo, cand2, cand3, bestd);
    k_gather <<<NROWS / 4, 256, 0, stream>>>(w, idxo, bestd, xnorm, out, hist, lossp);
    k_loss1  <<<64, 256, 0, stream>>>(lossp, part);
    k_final2 <<<1, 256, 0, stream>>>(part, hist, out);
}

// Round 7
// 290.808 us; speedup vs baseline: 5.5864x; 1.4037x over previous
//
#include <hip/hip_runtime.h>
#include <hip/hip_fp16.h>
#include <cmath>

#define NROWS  65536
#define DIM    512
#define KCODES 2048
#define NDTOT  33554432LL   // NROWS*DIM
// refine trigger: f16-product error (14*sigma = 0.0625) + key truncation (<=0.5)
#define MARGIN_P 0.5625f

typedef __attribute__((ext_vector_type(8))) _Float16 f16x8;  // 8 f16 = 1 MFMA operand
typedef __attribute__((ext_vector_type(4))) float f32x4;

// branchless sorted-top3 insert of packed key v (u32 min/max keep regs, no addresses)
#define KINS3(K1,K2,K3,V) do {                       \
    unsigned int _v = (V);                           \
    unsigned int _h1 = max((K1), _v); (K1) = min((K1), _v); \
    unsigned int _h2 = max((K2), _h1); (K2) = min((K2), _h1); \
    (K3) = min((K3), _h2);                           \
} while (0)

__device__ inline void gll16(const void* g, void* l) {
    __builtin_amdgcn_global_load_lds(
        (const __attribute__((address_space(1))) void*)g,
        (__attribute__((address_space(3))) void*)l, 16, 0, 0);
}

// ---------------- kernel 1: fp32 -> f16 plane in fragment-lane order, fused row norm ----
// tile (per 128-row block rb, per ks64 of 64 dims): 16384 B =
//   [ksub 2][frow 8][lane 64][16B]; lane = (k32sub)*16 + row%16, frow=(row%128)/16.
// Matches mfma_f32_16x16x32_f16 A/B frags (lane l: row l&15, k=(l>>4)*8+r).
__global__ __launch_bounds__(256) void k_prep(const float* __restrict__ src,
                                              char* __restrict__ dst,
                                              float* __restrict__ norms) {
    long gid = (long)blockIdx.x * 256 + threadIdx.x;
    int row = (int)(gid >> 6);
    int k8  = (int)(gid & 63);           // chunk of 8 dims
    const float4* s = (const float4*)(src + (size_t)row * DIM + k8 * 8);
    float4 v0 = s[0], v1 = s[1];
    float vv[8] = {v0.x, v0.y, v0.z, v0.w, v1.x, v1.y, v1.z, v1.w};
    unsigned int hw[4];
    float nrm = 0.f;
    #pragma unroll
    for (int j = 0; j < 4; ++j) {
        unsigned int h0 = __half_as_ushort(__float2half_rn(vv[2*j]));
        unsigned int h1 = __half_as_ushort(__float2half_rn(vv[2*j+1]));
        hw[j] = h0 | (h1 << 16);
        nrm = fmaf(vv[2*j], vv[2*j], nrm);
        nrm = fmaf(vv[2*j+1], vv[2*j+1], nrm);
    }
    int rb = row >> 7, frow = (row >> 4) & 7;
    int k32 = k8 >> 2, sub = k8 & 3;
    int ksub = k32 & 1, ks64 = k32 >> 1;
    int l = sub * 16 + (row & 15);
    size_t off = (size_t)(rb * 8 + ks64) * 16384 + (size_t)ksub * 8192
               + (size_t)frow * 1024 + (size_t)l * 16;
    *(uint4*)(dst + off) = make_uint4(hw[0], hw[1], hw[2], hw[3]);
    #pragma unroll
    for (int o = 32; o; o >>= 1) nrm += __shfl_xor(nrm, o, 64);
    if ((threadIdx.x & 63) == 0) norms[row] = nrm;
}

// ---------------- kernel 2: f16 MFMA GEMM + fused packed top-3 argmin ----------------
// key = (bits(dist+1024) & ~0x7FF) | col : monotone in dist (positive range),
// ties resolve to lowest col via umin. State = 3 u32 per slot (48 regs, no spill).
__global__ __launch_bounds__(256, 2) void k_gemm(const char* __restrict__ xp,
                                                 const char* __restrict__ wp,
                                                 const float* __restrict__ wnorm,
                                                 int* __restrict__ idxo,
                                                 int* __restrict__ cand2o,
                                                 int* __restrict__ cand3o,
                                                 float* __restrict__ bestd) {
    __shared__ char smem[65536];   // As[2] @0,16384 ; Bs[2] @32768,49152
    const int tid = threadIdx.x;
    const int lane = tid & 63;
    const int wid = tid >> 6;
    const int wr = wid >> 1, wc = wid & 1;
    const int rb = blockIdx.x;
    const char* xsrc = xp + (size_t)rb * (8 * 16384);

    f32x4 acc[4][4];
    #pragma unroll
    for (int i = 0; i < 4; ++i)
        #pragma unroll
        for (int j = 0; j < 4; ++j) acc[i][j] = (f32x4){0.f, 0.f, 0.f, 0.f};

    unsigned int k1[16], k2[16], k3[16];
    #pragma unroll
    for (int s = 0; s < 16; ++s) { k1[s] = k2[s] = k3[s] = 0xFFFFFFFFu; }

    auto STAGE = [&](int t) {
        int cb = t >> 3, ks = t & 7, p = t & 1;
        const char* bsrc = wp + (size_t)(cb * 8 + ks) * 16384;
        const char* asrc = xsrc + (size_t)ks * 16384;
        char* bdst = smem + 32768 + p * 16384;
        char* adst = smem + p * 16384;
        #pragma unroll
        for (int i = 0; i < 4; ++i) {
            int c = wid * 4 + i;   // 16 chunks of 1024B per matrix, 4 per wave
            gll16(bsrc + c * 1024 + lane * 16, bdst + c * 1024);
            gll16(asrc + c * 1024 + lane * 16, adst + c * 1024);
        }
    };

    auto COMPUTE = [&](int t) {
        int p = t & 1;
        const char* A = smem + p * 16384;
        const char* B = smem + 32768 + p * 16384;
        #pragma unroll
        for (int ksub = 0; ksub < 2; ++ksub) {
            f16x8 ah[4];
            #pragma unroll
            for (int fr = 0; fr < 4; ++fr)
                ah[fr] = *(const f16x8*)(A + ksub * 8192 + (wr * 4 + fr) * 1024 + lane * 16);
            #pragma unroll
            for (int fc = 0; fc < 4; ++fc) {
                f16x8 bh = *(const f16x8*)(B + ksub * 8192 + (wc * 4 + fc) * 1024 + lane * 16);
                #pragma unroll
                for (int fr = 0; fr < 4; ++fr)
                    acc[fr][fc] = __builtin_amdgcn_mfma_f32_16x16x32_f16(ah[fr], bh, acc[fr][fc], 0, 0, 0);
            }
        }
    };

    auto EPILOGUE = [&](int cb) {
        #pragma unroll
        for (int fc = 0; fc < 4; ++fc) {
            unsigned int col = (unsigned)(cb * 128 + wc * 64 + fc * 16 + (lane & 15));
            float wnb = wnorm[col] + 1024.f;     // bias keeps key positive, exp band 2^10
            #pragma unroll
            for (int fr = 0; fr < 4; ++fr) {
                #pragma unroll
                for (int reg = 0; reg < 4; ++reg) {
                    float kd = fmaf(-2.f, acc[fr][fc][reg], wnb);
                    unsigned int key = (__float_as_uint(kd) & 0xFFFFF800u) | col;
                    int s = fr * 4 + reg;
                    KINS3(k1[s], k2[s], k3[s], key);
                }
                acc[fr][fc] = (f32x4){0.f, 0.f, 0.f, 0.f};
            }
        }
    };

    STAGE(0);
    __syncthreads();
    #pragma unroll 2
    for (int t = 0; t < 128; ++t) {
        if (t < 127) STAGE(t + 1);
        COMPUTE(t);
        if ((t & 7) == 7) EPILOGUE(t >> 3);
        __syncthreads();
    }

    // butterfly top-3 merge across the 16 column-lanes of each slot.
    // merge of two sorted triples (a1..a3),(b1..b3):
    //   x1=min(a1,b1) y1=max(a1,b1) x2=min(a2,b2) y2=max(a2,b2) x3=min(a3,b3)
    //   m1=x1; m2=min(y1,x2); m3=min(max(y1,x2), min(x3,y2))
    #pragma unroll
    for (int s = 0; s < 16; ++s) {
        #pragma unroll
        for (int off = 1; off < 16; off <<= 1) {
            unsigned int b1 = (unsigned)__shfl_xor((int)k1[s], off, 16);
            unsigned int b2 = (unsigned)__shfl_xor((int)k2[s], off, 16);
            unsigned int b3 = (unsigned)__shfl_xor((int)k3[s], off, 16);
            unsigned int x1 = min(k1[s], b1), y1 = max(k1[s], b1);
            unsigned int x2 = min(k2[s], b2), y2 = max(k2[s], b2);
            unsigned int x3 = min(k3[s], b3);
            k1[s] = x1;
            k2[s] = min(y1, x2);
            k3[s] = min(max(y1, x2), min(x3, y2));
        }
    }
    // lane (lane&15)==s owns slot s; static-unrolled select (rule #20)
    unsigned int m1 = 0, m2 = 0, m3 = 0;
    #pragma unroll
    for (int s = 0; s < 16; ++s) {
        bool mine = (lane & 15) == s;
        m1 = mine ? k1[s] : m1;
        m2 = mine ? k2[s] : m2;
        m3 = mine ? k3[s] : m3;
    }
    int sl = lane & 15;
    int rowl = wr * 64 + (sl >> 2) * 16 + (lane >> 4) * 4 + (sl & 3);
    ((uint4*)smem)[rowl * 2 + wc] = make_uint4(m1, m2, m3, 0u);
    __syncthreads();
    if (tid < 128) {
        uint4 a = ((const uint4*)smem)[tid * 2 + 0];
        uint4 b = ((const uint4*)smem)[tid * 2 + 1];
        unsigned int x1 = min(a.x, b.x), y1 = max(a.x, b.x);
        unsigned int x2 = min(a.y, b.y), y2 = max(a.y, b.y);
        unsigned int x3 = min(a.z, b.z);
        unsigned int K1 = x1;
        unsigned int K2 = min(y1, x2);
        unsigned int K3 = min(max(y1, x2), min(x3, y2));
        float f1 = __uint_as_float(K1 & 0xFFFFF800u) - 1024.f;
        float f2 = __uint_as_float(K2 & 0xFFFFF800u) - 1024.f;
        float f3 = __uint_as_float(K3 & 0xFFFFF800u) - 1024.f;
        int row = rb * 128 + tid;
        idxo[row]   = (int)(K1 & 0x7FFu);
        bestd[row]  = f1;
        cand2o[row] = (f2 - f1 < MARGIN_P) ? (int)(K2 & 0x7FFu) : -1;
        cand3o[row] = (f3 - f1 < MARGIN_P) ? (int)(K3 & 0x7FFu) : -1;
    }
}

// ---------------- kernel 3: fused fp64 refine + gather + loss partial + histogram ----
// one wave per row; flagged rows re-resolve up to 3 candidates in fp64.
__global__ __launch_bounds__(256) void k_gather2(const float* __restrict__ x,
                                                 const float* __restrict__ w,
                                                 const int* __restrict__ idxo,
                                                 const int* __restrict__ cand2o,
                                                 const int* __restrict__ cand3o,
                                                 const float* __restrict__ bestd,
                                                 const float* __restrict__ xnorm,
                                                 float* __restrict__ out,
                                                 int* __restrict__ hist,
                                                 double* __restrict__ part) {
    __shared__ double red[4];
    int wid = threadIdx.x >> 6, lane = threadIdx.x & 63;
    int n = blockIdx.x * 4 + wid;
    int c1 = idxo[n];
    int c2 = cand2o[n];
    int cfin = c1;
    double dist = (double)bestd[n];
    if (c2 >= 0) {
        int c3 = cand3o[n];
        int c3e = (c3 < 0) ? c1 : c3;
        const float* xr = x + (size_t)n * DIM;
        const float* w1 = w + (size_t)c1 * DIM;
        const float* w2 = w + (size_t)c2 * DIM;
        const float* w3 = w + (size_t)c3e * DIM;
        double s1 = 0.0, s2 = 0.0, s3 = 0.0;
        #pragma unroll
        for (int j = 0; j < DIM / 64; ++j) {
            int d = lane + 64 * j;
            double xv = (double)xr[d];
            double a = (double)w1[d], b = (double)w2[d], c = (double)w3[d];
            s1 += a * a - 2.0 * xv * a;
            s2 += b * b - 2.0 * xv * b;
            s3 += c * c - 2.0 * xv * c;
        }
        #pragma unroll
        for (int off = 32; off; off >>= 1) {
            s1 += __shfl_xor(s1, off, 64);
            s2 += __shfl_xor(s2, off, 64);
            s3 += __shfl_xor(s3, off, 64);
        }
        double bs = s1; int bi = c1;
        if (s2 < bs || (s2 == bs && c2 < bi)) { bs = s2; bi = c2; }
        if (c3 >= 0 && (s3 < bs || (s3 == bs && c3 < bi))) { bs = s3; bi = c3; }
        cfin = bi;
        dist = bs;
    }
    // gather winner row (uniform across wave)
    const float* wq = w + (size_t)cfin * DIM;
    float* oq = out + 1 + (size_t)n * DIM;   // quantized_st == quantized numerically
    #pragma unroll
    for (int j = 0; j < DIM / 64; ++j) {
        int d = j * 64 + lane;
        oq[d] = wq[d];
    }
    if (lane == 0) {
        red[wid] = dist + (double)xnorm[n];  // ||x-w||^2 = (||w||^2-2xw) + ||x||^2
        atomicAdd(&hist[cfin], 1);
        out[2 + NDTOT + n] = (float)cfin;
    }
    __syncthreads();
    if (threadIdx.x == 0)
        part[blockIdx.x] = red[0] + red[1] + red[2] + red[3];
}

// ---------------- kernel 4: deterministic finalize (loss + perplexity) ----------------
__global__ __launch_bounds__(256) void k_final2(const double* __restrict__ part,
                                                const int* __restrict__ hist,
                                                float* __restrict__ out) {
    __shared__ double sm[256];
    int t = threadIdx.x;
    double s = 0.0;
    for (int i = t; i < NROWS / 4; i += 256) s += part[i];
    sm[t] = s; __syncthreads();
    for (int off = 128; off; off >>= 1) { if (t < off) sm[t] += sm[t + off]; __syncthreads(); }
    if (t == 0) out[0] = (float)(sm[0] * 0.25 / (double)NDTOT);
    __syncthreads();
    double e = 0.0;
    for (int k = t; k < KCODES; k += 256) {
        double p = (double)hist[k] / (double)NROWS;
        e -= p * log(p + 1e-10);
    }
    sm[t] = e; __syncthreads();
    for (int off = 128; off; off >>= 1) { if (t < off) sm[t] += sm[t + off]; __syncthreads(); }
    if (t == 0) out[1 + NDTOT] = (float)exp(sm[0]);
}

extern "C" void kernel_launch(void* const* d_in, const int* in_sizes, int n_in,
                              void* d_out, int out_size, void* d_ws, size_t ws_size,
                              hipStream_t stream) {
    const float* x = (const float*)d_in[0];   // [64,1024,512] fp32
    const float* w = (const float*)d_in[1];   // [2048,512] fp32
    float* out = (float*)d_out;
    char* ws = (char*)d_ws;

    // xp (64 MB f16 fragment-ordered) lives in the d_out quantized region:
    // k_gemm consumes it before k_gather2 overwrites every byte with outputs.
    char* xp = (char*)d_out + 16;

    char*   wp    = ws;                            // 2 MB
    float*  wnorm = (float*)(ws + 2097152);        // 8 KB
    int*    idxo  = (int*)(ws + 2105344);          // 256 KB
    int*    cand2 = (int*)(ws + 2367488);          // 256 KB
    int*    cand3 = (int*)(ws + 2629632);          // 256 KB
    int*    hist  = (int*)(ws + 2891776);          // 8 KB
    float*  xnorm = (float*)(ws + 2899968);        // 256 KB
    float*  bestd = (float*)(ws + 3162112);        // 256 KB
    double* part  = (double*)(ws + 3424256);       // 128 KB

    hipMemsetAsync(hist, 0, KCODES * sizeof(int), stream);
    k_prep   <<<(KCODES * 64) / 256, 256, 0, stream>>>(w, wp, wnorm);
    k_prep   <<<(NROWS * 64) / 256, 256, 0, stream>>>(x, xp, xnorm);
    k_gemm   <<<NROWS / 128, 256, 0, stream>>>(xp, wp, wnorm, idxo, cand2, cand3, bestd);
    k_gather2<<<NROWS / 4, 256, 0, stream>>>(x, w, idxo, cand2, cand3, bestd, xnorm, out, hist, part);
    k_final2 <<<1, 256, 0, stream>>>(part, hist, out);
}